// Round 16
// baseline (1432.692 us; speedup 1.0000x reference)
//
#include <hip/hip_runtime.h>

#define NI 8
#define NH 64
#define NO 8
#define NB 256
#define NT 2048
#define NBLK (NB / 2)   // 2 batch chains per block

typedef float v2f __attribute__((ext_vector_type(2)));

__device__ __forceinline__ v2f fma2(v2f a, v2f b, v2f c) {
    return __builtin_elementwise_fma(a, b, c);
}

// tanh(s) = 1 - 2/(exp(2s)+1); safe at +-inf
__device__ __forceinline__ float tanh_fast(float s) {
    float e = __expf(2.0f * s);
    return fmaf(-2.0f, __builtin_amdgcn_rcpf(e + 1.0f), 1.0f);
}

// R15 conveyor with TWO independent batch chains interleaved per wave.
// R15 counters: each wave busy only ~40% of the 858-cyc period; the rest is
// LDS round-trip + tanh latency a single serial chain can't fill. A second
// independent chain (weights SHARED in registers) turns stall into issue.
//   A: dual h0 chains + pi production   C: dual h1 chains + FC + stores
//   D: dual u producers (4-step windows, 2-window lookahead)
// One flag set (both chains lockstep); rings duplicated per chain.
__attribute__((amdgpu_waves_per_eu(1, 1)))
__global__ void __launch_bounds__(192) rnn_dual(
    const float* __restrict__ x,
    const float* __restrict__ W_ih0, const float* __restrict__ W_hh0,
    const float* __restrict__ b_ih0, const float* __restrict__ b_hh0,
    const float* __restrict__ W_ih1, const float* __restrict__ W_hh1,
    const float* __restrict__ b_ih1, const float* __restrict__ b_hh1,
    const float* __restrict__ W_fc,  const float* __restrict__ b_fc,
    float* __restrict__ out)
{
    const int blk  = blockIdx.x;
    const int b0   = 2 * blk, b1 = 2 * blk + 1;
    const int tid  = threadIdx.x;
    const int wid  = tid >> 6;
    const int lane = tid & 63;

    __shared__ __align__(16) float ur[2][32][NH];    // D -> A rings
    __shared__ __align__(16) float pir[2][32][NH];   // A -> C rings
    __shared__ __align__(16) float h0s[2][NH];       // A-private gather buffers
    __shared__ __align__(16) float h1s[2][NH];       // C-private gather buffers
    __shared__ int fa, fc2, fu;

    if (tid == 0) { fa = -1; fc2 = -1; fu = -1; }
    __syncthreads();

    volatile int* vfa  = &fa;
    volatile int* vfc2 = &fc2;
    volatile int* vfu  = &fu;

    const float* xb0   = x + (size_t)b0 * NT * NI;
    const float* xb1   = x + (size_t)b1 * NT * NI;
    float*       outb0 = out + (size_t)b0 * NT * NO;
    float*       outb1 = out + (size_t)b1 * NT * NO;
    const size_t hid   = (size_t)NB * NT * NO;

    if (wid == 0) {
        // ========== wave A: dual h0 chains + pi production ==========
        v2f wh[NH / 2], wi[NH / 2];
        #pragma unroll
        for (int k = 0; k < NH / 2; ++k) {
            wh[k] = v2f{W_hh0[lane * NH + 2 * k], W_hh0[lane * NH + 2 * k + 1]};
            wi[k] = v2f{W_ih1[lane * NH + 2 * k], W_ih1[lane * NH + 2 * k + 1]};
        }
        #pragma unroll
        for (int k = 0; k < NH / 2; ++k) { asm("" : "+v"(wh[k])); asm("" : "+v"(wi[k])); }

        float h0n0 = 0.0f, h0n1 = 0.0f, dI0 = 0.0f, dI1 = 0.0f;

        while (*vfu < 11) {}                     // D's prologue (slots 0..11)
        asm volatile("" ::: "memory");
        float uv0n = ur[0][0][lane], uv1n = ur[1][0][lane];

        for (int t = 0; t < NT; ++t) {
            if ((t & 7) == 0) {
                const int needU = (t + 8 < NT) ? t + 8 : NT - 1;
                while (*vfu < needU) {}
                while (*vfc2 < t - 27) {}        // pir slot reuse vs C
                asm volatile("" ::: "memory");
            }
            h0s[0][lane] = h0n0;                 // h0[t-1], both chains
            h0s[1][lane] = h0n1;
            if (t >= 2) {                        // deferred pi writes
                pir[0][(t - 2) & 31][lane] = dI0;
                pir[1][(t - 2) & 31][lane] = dI1;
            }
            const float uv0c = uv0n, uv1c = uv1n;
            uv0n = ur[0][(t + 1) & 31][lane];
            uv1n = ur[1][(t + 1) & 31][lane];

            const float4* hp0 = (const float4*)&h0s[0][0];
            const float4* hp1 = (const float4*)&h0s[1][0];
            v2f W0a={0,0},W0b={0,0},W0c={0,0},W0d={0,0};
            v2f I0a={0,0},I0b={0,0},I0c={0,0},I0d={0,0};
            v2f W1a={0,0},W1b={0,0},W1c={0,0},W1d={0,0};
            v2f I1a={0,0},I1b={0,0},I1c={0,0},I1d={0,0};
            #pragma unroll
            for (int k = 0; k < 16; ++k) {
                const float4 g0 = hp0[k];
                const float4 g1 = hp1[k];
                const v2f l0 = {g0.x, g0.y}, u0 = {g0.z, g0.w};
                const v2f l1 = {g1.x, g1.y}, u1 = {g1.z, g1.w};
                if (k & 1) {
                    W0c = fma2(l0, wh[2*k], W0c); W0d = fma2(u0, wh[2*k+1], W0d);
                    I0c = fma2(l0, wi[2*k], I0c); I0d = fma2(u0, wi[2*k+1], I0d);
                    W1c = fma2(l1, wh[2*k], W1c); W1d = fma2(u1, wh[2*k+1], W1d);
                    I1c = fma2(l1, wi[2*k], I1c); I1d = fma2(u1, wi[2*k+1], I1d);
                } else {
                    W0a = fma2(l0, wh[2*k], W0a); W0b = fma2(u0, wh[2*k+1], W0b);
                    I0a = fma2(l0, wi[2*k], I0a); I0b = fma2(u0, wi[2*k+1], I0b);
                    W1a = fma2(l1, wh[2*k], W1a); W1b = fma2(u1, wh[2*k+1], W1b);
                    I1a = fma2(l1, wi[2*k], I1a); I1b = fma2(u1, wi[2*k+1], I1b);
                }
            }
            if (t & 1) {                         // publish: writes long returned
                asm volatile("s_waitcnt lgkmcnt(0)" ::: "memory");
                *vfa = t - 2;
            }
            const v2f sW0 = (W0a + W0b) + (W0c + W0d);
            const v2f sI0 = (I0a + I0b) + (I0c + I0d);
            const v2f sW1 = (W1a + W1b) + (W1c + W1d);
            const v2f sI1 = (I1a + I1b) + (I1c + I1d);
            dI0 = sI0.x + sI0.y;
            dI1 = sI1.x + sI1.y;
            h0n0 = tanh_fast(sW0.x + sW0.y + uv0c);
            h0n1 = tanh_fast(sW1.x + sW1.y + uv1c);
        }

        // epilogue: pi[NT-2] (pending) and pi[NT-1] (fresh gather), both chains
        while (*vfc2 < NT - 33) {}
        asm volatile("" ::: "memory");
        pir[0][(NT - 2) & 31][lane] = dI0;
        pir[1][(NT - 2) & 31][lane] = dI1;
        h0s[0][lane] = h0n0;
        h0s[1][lane] = h0n1;
        {
            const float4* hp0 = (const float4*)&h0s[0][0];
            const float4* hp1 = (const float4*)&h0s[1][0];
            v2f I0a={0,0},I0b={0,0},I0c={0,0},I0d={0,0};
            v2f I1a={0,0},I1b={0,0},I1c={0,0},I1d={0,0};
            #pragma unroll
            for (int k = 0; k < 16; ++k) {
                const float4 g0 = hp0[k];
                const float4 g1 = hp1[k];
                const v2f l0 = {g0.x, g0.y}, u0 = {g0.z, g0.w};
                const v2f l1 = {g1.x, g1.y}, u1 = {g1.z, g1.w};
                if (k & 1) {
                    I0c = fma2(l0, wi[2*k], I0c); I0d = fma2(u0, wi[2*k+1], I0d);
                    I1c = fma2(l1, wi[2*k], I1c); I1d = fma2(u1, wi[2*k+1], I1d);
                } else {
                    I0a = fma2(l0, wi[2*k], I0a); I0b = fma2(u0, wi[2*k+1], I0b);
                    I1a = fma2(l1, wi[2*k], I1a); I1b = fma2(u1, wi[2*k+1], I1b);
                }
            }
            const v2f sI0 = (I0a + I0b) + (I0c + I0d);
            const v2f sI1 = (I1a + I1b) + (I1c + I1d);
            pir[0][(NT - 1) & 31][lane] = sI0.x + sI0.y;
            pir[1][(NT - 1) & 31][lane] = sI1.x + sI1.y;
        }
        asm volatile("s_waitcnt lgkmcnt(0)" ::: "memory");
        *vfa = NT - 1;
        out[hid + (size_t)b0 * NH + lane] = h0n0;                   // h0 finals
        out[hid + (size_t)b1 * NH + lane] = h0n1;
    } else if (wid == 1) {
        // ========== wave C: dual h1 chains + FC + stores ==========
        const int o = lane & 7;
        v2f wh1[NH / 2], wf[NH / 2];
        #pragma unroll
        for (int k = 0; k < NH / 2; ++k) {
            wh1[k] = v2f{W_hh1[lane * NH + 2 * k], W_hh1[lane * NH + 2 * k + 1]};
            wf[k]  = v2f{W_fc[o * NH + 2 * k],     W_fc[o * NH + 2 * k + 1]};
        }
        #pragma unroll
        for (int k = 0; k < NH / 2; ++k) { asm("" : "+v"(wh1[k])); asm("" : "+v"(wf[k])); }
        const float bias1 = b_ih1[lane] + b_hh1[lane];
        const float bfc   = b_fc[o];
        float h1n0 = 0.0f, h1n1 = 0.0f;

        while (*vfa < 1) {}                      // pi[0] ready
        asm volatile("" ::: "memory");
        float pv0n = pir[0][0][lane], pv1n = pir[1][0][lane];

        for (int t = 0; t < NT; ++t) {
            if ((t & 3) == 0) {                  // covers prefetch through t+4
                const int need = (t + 4 < NT) ? t + 4 : NT - 1;
                while (*vfa < need) {}
                asm volatile("" ::: "memory");
            }
            h1s[0][lane] = h1n0;                 // h1[t-1], both chains
            h1s[1][lane] = h1n1;
            const float pv0c = pv0n, pv1c = pv1n;
            pv0n = pir[0][(t + 1) & 31][lane];
            pv1n = pir[1][(t + 1) & 31][lane];

            const float4* hp0 = (const float4*)&h1s[0][0];
            const float4* hp1 = (const float4*)&h1s[1][0];
            v2f W0a={0,0},W0b={0,0},W0c={0,0},W0d={0,0};
            v2f F0a={0,0},F0b={0,0},F0c={0,0},F0d={0,0};
            v2f W1a={0,0},W1b={0,0},W1c={0,0},W1d={0,0};
            v2f F1a={0,0},F1b={0,0},F1c={0,0},F1d={0,0};
            #pragma unroll
            for (int k = 0; k < 16; ++k) {
                const float4 g0 = hp0[k];
                const float4 g1 = hp1[k];
                const v2f l0 = {g0.x, g0.y}, u0 = {g0.z, g0.w};
                const v2f l1 = {g1.x, g1.y}, u1 = {g1.z, g1.w};
                if (k & 1) {
                    W0c = fma2(l0, wh1[2*k], W0c); W0d = fma2(u0, wh1[2*k+1], W0d);
                    F0c = fma2(l0, wf[2*k],  F0c); F0d = fma2(u0, wf[2*k+1],  F0d);
                    W1c = fma2(l1, wh1[2*k], W1c); W1d = fma2(u1, wh1[2*k+1], W1d);
                    F1c = fma2(l1, wf[2*k],  F1c); F1d = fma2(u1, wf[2*k+1],  F1d);
                } else {
                    W0a = fma2(l0, wh1[2*k], W0a); W0b = fma2(u0, wh1[2*k+1], W0b);
                    F0a = fma2(l0, wf[2*k],  F0a); F0b = fma2(u0, wf[2*k+1],  F0b);
                    W1a = fma2(l1, wh1[2*k], W1a); W1b = fma2(u1, wh1[2*k+1], W1b);
                    F1a = fma2(l1, wf[2*k],  F1a); F1b = fma2(u1, wf[2*k+1],  F1b);
                }
            }
            const v2f sW0 = (W0a + W0b) + (W0c + W0d);
            const v2f sF0 = (F0a + F0b) + (F0c + F0d);
            const v2f sW1 = (W1a + W1b) + (W1c + W1d);
            const v2f sF1 = (F1a + F1b) + (F1c + F1d);
            if (t > 0) {                         // FC(t-1): lanes 0-7 chain0, 8-15 chain1
                if (lane < NO)
                    outb0[(size_t)(t - 1) * NO + o] = sF0.x + sF0.y + bfc;
                else if (lane < 2 * NO)
                    outb1[(size_t)(t - 1) * NO + o] = sF1.x + sF1.y + bfc;
            }
            h1n0 = tanh_fast(sW0.x + sW0.y + pv0c + bias1);
            h1n1 = tanh_fast(sW1.x + sW1.y + pv1c + bias1);
            if ((t & 3) == 3) {                  // consumption progress
                asm volatile("s_waitcnt lgkmcnt(0)" ::: "memory");
                *vfc2 = t;
            }
        }

        // epilogue: FC(NT-1) both chains
        h1s[0][lane] = h1n0;
        h1s[1][lane] = h1n1;
        {
            const float4* hp0 = (const float4*)&h1s[0][0];
            const float4* hp1 = (const float4*)&h1s[1][0];
            v2f F0a={0,0},F0b={0,0},F0c={0,0},F0d={0,0};
            v2f F1a={0,0},F1b={0,0},F1c={0,0},F1d={0,0};
            #pragma unroll
            for (int k = 0; k < 16; ++k) {
                const float4 g0 = hp0[k];
                const float4 g1 = hp1[k];
                const v2f l0 = {g0.x, g0.y}, u0 = {g0.z, g0.w};
                const v2f l1 = {g1.x, g1.y}, u1 = {g1.z, g1.w};
                if (k & 1) {
                    F0c = fma2(l0, wf[2*k], F0c); F0d = fma2(u0, wf[2*k+1], F0d);
                    F1c = fma2(l1, wf[2*k], F1c); F1d = fma2(u1, wf[2*k+1], F1d);
                } else {
                    F0a = fma2(l0, wf[2*k], F0a); F0b = fma2(u0, wf[2*k+1], F0b);
                    F1a = fma2(l1, wf[2*k], F1a); F1b = fma2(u1, wf[2*k+1], F1b);
                }
            }
            const v2f sF0 = (F0a + F0b) + (F0c + F0d);
            const v2f sF1 = (F1a + F1b) + (F1c + F1d);
            if (lane < NO)
                outb0[(size_t)(NT - 1) * NO + o] = sF0.x + sF0.y + bfc;
            else if (lane < 2 * NO)
                outb1[(size_t)(NT - 1) * NO + o] = sF1.x + sF1.y + bfc;
        }
        out[hid + (size_t)NB * NH + (size_t)b0 * NH + lane] = h1n0;  // h1 finals
        out[hid + (size_t)NB * NH + (size_t)b1 * NH + lane] = h1n1;
    } else if (wid == 2) {
        // ========== wave D: dual u producers, 4-step windows ==========
        float wih0r[NI];
        #pragma unroll
        for (int i = 0; i < NI; ++i) wih0r[i] = W_ih0[lane * NI + i];
        const float bias0 = b_ih0[lane] + b_hh0[lane];

        // prologue: windows 0..2 (steps 0..11), both chains, direct loads
        #pragma unroll
        for (int s = 0; s < 12; ++s) {
            const float4 a0 = *(const float4*)(xb0 + (size_t)s * NI);
            const float4 a1 = *(const float4*)(xb0 + (size_t)s * NI + 4);
            const float4 c0 = *(const float4*)(xb1 + (size_t)s * NI);
            const float4 c1 = *(const float4*)(xb1 + (size_t)s * NI + 4);
            float u0 = bias0, u1 = bias0;
            u0 = fmaf(a0.x, wih0r[0], u0); u0 = fmaf(a0.y, wih0r[1], u0);
            u0 = fmaf(a0.z, wih0r[2], u0); u0 = fmaf(a0.w, wih0r[3], u0);
            u0 = fmaf(a1.x, wih0r[4], u0); u0 = fmaf(a1.y, wih0r[5], u0);
            u0 = fmaf(a1.z, wih0r[6], u0); u0 = fmaf(a1.w, wih0r[7], u0);
            u1 = fmaf(c0.x, wih0r[0], u1); u1 = fmaf(c0.y, wih0r[1], u1);
            u1 = fmaf(c0.z, wih0r[2], u1); u1 = fmaf(c0.w, wih0r[3], u1);
            u1 = fmaf(c1.x, wih0r[4], u1); u1 = fmaf(c1.y, wih0r[5], u1);
            u1 = fmaf(c1.z, wih0r[6], u1); u1 = fmaf(c1.w, wih0r[7], u1);
            ur[0][s][lane] = u0;
            ur[1][s][lane] = u1;
        }
        asm volatile("s_waitcnt lgkmcnt(0)" ::: "memory");
        *vfu = 11;

        // xc = window 3, xn = window 4 (4 steps each, both chains)
        float4 xc0[8], xc1[8], xn0[8], xn1[8];
        #pragma unroll
        for (int j = 0; j < 4; ++j) {
            xc0[2*j]   = *(const float4*)(xb0 + (size_t)(12 + j) * NI);
            xc0[2*j+1] = *(const float4*)(xb0 + (size_t)(12 + j) * NI + 4);
            xc1[2*j]   = *(const float4*)(xb1 + (size_t)(12 + j) * NI);
            xc1[2*j+1] = *(const float4*)(xb1 + (size_t)(12 + j) * NI + 4);
        }
        #pragma unroll
        for (int j = 0; j < 4; ++j) {
            xn0[2*j]   = *(const float4*)(xb0 + (size_t)(16 + j) * NI);
            xn0[2*j+1] = *(const float4*)(xb0 + (size_t)(16 + j) * NI + 4);
            xn1[2*j]   = *(const float4*)(xb1 + (size_t)(16 + j) * NI);
            xn1[2*j+1] = *(const float4*)(xb1 + (size_t)(16 + j) * NI + 4);
        }

        for (int w = 3; w < NT / 4; ++w) {
            while (*vfa < 4 * w - 20) {}         // ur slot reuse vs A
            asm volatile("" ::: "memory");
            #pragma unroll
            for (int j = 0; j < 4; ++j) {
                float u0 = bias0, u1 = bias0;
                u0 = fmaf(xc0[2*j].x,   wih0r[0], u0); u0 = fmaf(xc0[2*j].y,   wih0r[1], u0);
                u0 = fmaf(xc0[2*j].z,   wih0r[2], u0); u0 = fmaf(xc0[2*j].w,   wih0r[3], u0);
                u0 = fmaf(xc0[2*j+1].x, wih0r[4], u0); u0 = fmaf(xc0[2*j+1].y, wih0r[5], u0);
                u0 = fmaf(xc0[2*j+1].z, wih0r[6], u0); u0 = fmaf(xc0[2*j+1].w, wih0r[7], u0);
                u1 = fmaf(xc1[2*j].x,   wih0r[0], u1); u1 = fmaf(xc1[2*j].y,   wih0r[1], u1);
                u1 = fmaf(xc1[2*j].z,   wih0r[2], u1); u1 = fmaf(xc1[2*j].w,   wih0r[3], u1);
                u1 = fmaf(xc1[2*j+1].x, wih0r[4], u1); u1 = fmaf(xc1[2*j+1].y, wih0r[5], u1);
                u1 = fmaf(xc1[2*j+1].z, wih0r[6], u1); u1 = fmaf(xc1[2*j+1].w, wih0r[7], u1);
                ur[0][(4 * w + j) & 31][lane] = u0;
                ur[1][(4 * w + j) & 31][lane] = u1;
            }
            asm volatile("s_waitcnt lgkmcnt(0)" ::: "memory");
            *vfu = 4 * w + 3;
            #pragma unroll
            for (int j = 0; j < 8; ++j) { xc0[j] = xn0[j]; xc1[j] = xn1[j]; }
            if (w + 2 < NT / 4) {                // load window w+2
                const size_t base = (size_t)(w + 2) * 4;
                #pragma unroll
                for (int j = 0; j < 4; ++j) {
                    xn0[2*j]   = *(const float4*)(xb0 + (base + j) * NI);
                    xn0[2*j+1] = *(const float4*)(xb0 + (base + j) * NI + 4);
                    xn1[2*j]   = *(const float4*)(xb1 + (base + j) * NI);
                    xn1[2*j+1] = *(const float4*)(xb1 + (base + j) * NI + 4);
                }
            }
        }
    }
}

extern "C" void kernel_launch(void* const* d_in, const int* in_sizes, int n_in,
                              void* d_out, int out_size, void* d_ws, size_t ws_size,
                              hipStream_t stream) {
    const float* x     = (const float*)d_in[0];
    const float* W_ih0 = (const float*)d_in[1];
    const float* W_hh0 = (const float*)d_in[2];
    const float* b_ih0 = (const float*)d_in[3];
    const float* b_hh0 = (const float*)d_in[4];
    const float* W_ih1 = (const float*)d_in[5];
    const float* W_hh1 = (const float*)d_in[6];
    const float* b_ih1 = (const float*)d_in[7];
    const float* b_hh1 = (const float*)d_in[8];
    const float* W_fc  = (const float*)d_in[9];
    const float* b_fc  = (const float*)d_in[10];

    rnn_dual<<<dim3(NBLK), dim3(192), 0, stream>>>(
        x, W_ih0, W_hh0, b_ih0, b_hh0,
        W_ih1, W_hh1, b_ih1, b_hh1, W_fc, b_fc,
        (float*)d_out);
}